// Round 3
// baseline (309.335 us; speedup 1.0000x reference)
//
#include <hip/hip_runtime.h>

#define H 1024
#define W 1024
#define K 11
#define RAD 5
#define TX 64            /* tile width  (outputs) */
#define TY 32            /* tile height (outputs) */
#define EY (TY + K - 1)  /* 42 H-plane rows */
#define NCG (TX / 4)     /* 16 column groups of 4 */

__global__ void zero_out_kernel(float* out) {
    if (threadIdx.x == 0) out[0] = 0.0f;
}

__device__ __forceinline__ float4 f4fma(float w, float4 v, float4 a) {
    return make_float4(fmaf(w, v.x, a.x), fmaf(w, v.y, a.y),
                       fmaf(w, v.z, a.z), fmaf(w, v.w, a.w));
}

__launch_bounds__(256, 3)
__global__ void ssim_kernel(const float* __restrict__ img1,
                            const float* __restrict__ img2,
                            const float* __restrict__ kern,
                            float* __restrict__ out,
                            float inv_n) {
    __shared__ float gsh[K];
    // Interleaved H-plane storage: [row][colgroup][plane] as float4 (4 cols).
    // 42*16*5*16 B = 52.5 KB -> 3 blocks/CU.
    __shared__ float4 planes[EY * NCG * 5];
    __shared__ float wsum[4];

    const int tid = threadIdx.x;
    const int bx = blockIdx.x;
    const int by = blockIdx.y;
    const int b  = blockIdx.z;

    // 1D gaussian factor = row sums of the normalized 2D kernel (exact).
    if (tid < K) {
        float s = 0.0f;
        #pragma unroll
        for (int j = 0; j < K; ++j) s += kern[tid * K + j];
        gsh[tid] = s;
    }
    __syncthreads();

    float gw[K];
    #pragma unroll
    for (int j = 0; j < K; ++j) gw[j] = gsh[j];

    const float* __restrict__ p1 = img1 + (size_t)b * H * W;
    const float* __restrict__ p2 = img2 + (size_t)b * H * W;
    const int row0 = by * TY - RAD;          // first raw/plane row
    const int colb = bx * TX - 8;            // 16B-aligned base col for cg=0

    // Fast path iff every load of this block is in-bounds.
    const bool fast = (colb >= 0) && (colb + (NCG - 1) * 4 + 19 < W) &&
                      (row0 >= 0) && (row0 + EY <= H);

    // ---- Horizontal pass: direct global loads (L1 serves halo), planes -> LDS ----
    for (int i = tid; i < EY * NCG; i += 256) {
        const int r  = i >> 4;
        const int cg = i & (NCG - 1);
        const int grow = row0 + r;
        const int gcb  = colb + cg * 4;      // window cols gcb..gcb+19; taps use [3..16]

        float x[20], y[20];
        if (fast) {
            const float4* px = (const float4*)(p1 + (size_t)grow * W + gcb);
            const float4* py = (const float4*)(p2 + (size_t)grow * W + gcb);
            #pragma unroll
            for (int q = 0; q < 5; ++q) {
                float4 vx = px[q];
                float4 vy = py[q];
                x[4*q+0] = vx.x; x[4*q+1] = vx.y; x[4*q+2] = vx.z; x[4*q+3] = vx.w;
                y[4*q+0] = vy.x; y[4*q+1] = vy.y; y[4*q+2] = vy.z; y[4*q+3] = vy.w;
            }
        } else {
            #pragma unroll
            for (int m = 0; m < 20; ++m) {
                int gc = gcb + m;
                float vx = 0.0f, vy = 0.0f;
                if ((unsigned)grow < (unsigned)H && (unsigned)gc < (unsigned)W) {
                    size_t idx = (size_t)grow * W + gc;
                    vx = p1[idx];
                    vy = p2[idx];
                }
                x[m] = vx; y[m] = vy;
            }
        }

        // Precompute per-column products once (indices 3..16 are used by taps).
        float xx[20], yy[20], xy[20];
        #pragma unroll
        for (int m = 3; m <= 16; ++m) {
            xx[m] = x[m] * x[m];
            yy[m] = y[m] * y[m];
            xy[m] = x[m] * y[m];
        }

        float amx[4] = {0,0,0,0}, amy[4] = {0,0,0,0};
        float axx[4] = {0,0,0,0}, ayy[4] = {0,0,0,0}, axy[4] = {0,0,0,0};
        #pragma unroll
        for (int j = 0; j < K; ++j) {
            float w = gw[j];
            #pragma unroll
            for (int k = 0; k < 4; ++k) {
                int m = 3 + k + j;
                amx[k] = fmaf(w, x[m],  amx[k]);
                amy[k] = fmaf(w, y[m],  amy[k]);
                axx[k] = fmaf(w, xx[m], axx[k]);
                ayy[k] = fmaf(w, yy[m], ayy[k]);
                axy[k] = fmaf(w, xy[m], axy[k]);
            }
        }

        float4* o = &planes[(r * NCG + cg) * 5];
        o[0] = make_float4(amx[0], amx[1], amx[2], amx[3]);
        o[1] = make_float4(amy[0], amy[1], amy[2], amy[3]);
        o[2] = make_float4(axx[0], axx[1], axx[2], axx[3]);
        o[3] = make_float4(ayy[0], ayy[1], ayy[2], ayy[3]);
        o[4] = make_float4(axy[0], axy[1], axy[2], axy[3]);
    }
    __syncthreads();

    // ---- Vertical pass: 128 threads, 4 cols x 4 rows each, b128 plane reads ----
    float acc = 0.0f;
    if (tid < 128) {
        const int cg = tid & (NCG - 1);
        const int rg = tid >> 4;             // 0..7, rows rg*4 .. rg*4+3

        float4 amx[4], amy[4], axx[4], ayy[4], axy[4];
        #pragma unroll
        for (int o = 0; o < 4; ++o) {
            amx[o] = make_float4(0,0,0,0); amy[o] = make_float4(0,0,0,0);
            axx[o] = make_float4(0,0,0,0); ayy[o] = make_float4(0,0,0,0);
            axy[o] = make_float4(0,0,0,0);
        }

        #pragma unroll
        for (int jj = 0; jj < 14; ++jj) {    // 4 rows + 10 halo
            const float4* pr = &planes[((rg * 4 + jj) * NCG + cg) * 5];
            float4 vmx = pr[0];
            float4 vmy = pr[1];
            float4 vxx = pr[2];
            float4 vyy = pr[3];
            float4 vxy = pr[4];
            #pragma unroll
            for (int o = 0; o < 4; ++o) {
                if (jj - o >= 0 && jj - o <= 10) {   // static after unroll
                    float w = gw[jj - o];
                    amx[o] = f4fma(w, vmx, amx[o]);
                    amy[o] = f4fma(w, vmy, amy[o]);
                    axx[o] = f4fma(w, vxx, axx[o]);
                    ayy[o] = f4fma(w, vyy, ayy[o]);
                    axy[o] = f4fma(w, vxy, axy[o]);
                }
            }
        }

        const float C1 = 1e-4f;
        const float C2 = 9e-4f;
        #pragma unroll
        for (int o = 0; o < 4; ++o) {
            float mxa[4] = {amx[o].x, amx[o].y, amx[o].z, amx[o].w};
            float mya[4] = {amy[o].x, amy[o].y, amy[o].z, amy[o].w};
            float xxa[4] = {axx[o].x, axx[o].y, axx[o].z, axx[o].w};
            float yya[4] = {ayy[o].x, ayy[o].y, ayy[o].z, ayy[o].w};
            float xya[4] = {axy[o].x, axy[o].y, axy[o].z, axy[o].w};
            #pragma unroll
            for (int k = 0; k < 4; ++k) {
                float mx = mxa[k], my = mya[k];
                float mx2 = mx * mx;
                float my2 = my * my;
                float mxy = mx * my;
                float sx2  = xxa[k] - mx2;
                float sy2  = yya[k] - my2;
                float sxyv = xya[k] - mxy;
                float num = (2.0f * mxy + C1) * (2.0f * sxyv + C2);
                float den = (mx2 + my2 + C1) * (sx2 + sy2 + C2);
                acc += num * __builtin_amdgcn_rcpf(den);
            }
        }
    }

    // ---- Wave butterfly reduce -> cross-wave via LDS -> one atomic ----
    for (int off = 32; off > 0; off >>= 1)
        acc += __shfl_down(acc, off, 64);
    if ((tid & 63) == 0) wsum[tid >> 6] = acc;
    __syncthreads();
    if (tid == 0) {
        float s = wsum[0] + wsum[1] + wsum[2] + wsum[3];
        atomicAdd(out, s * inv_n);
    }
}

extern "C" void kernel_launch(void* const* d_in, const int* in_sizes, int n_in,
                              void* d_out, int out_size, void* d_ws, size_t ws_size,
                              hipStream_t stream) {
    const float* img1 = (const float*)d_in[0];
    const float* img2 = (const float*)d_in[1];
    const float* kern = (const float*)d_in[2];
    float* out = (float*)d_out;

    const int B = in_sizes[0] / (H * W);
    const float inv_n = 1.0f / ((float)B * (float)H * (float)W);

    zero_out_kernel<<<dim3(1), dim3(64), 0, stream>>>(out);

    dim3 grid(W / TX, H / TY, B);
    ssim_kernel<<<grid, dim3(256), 0, stream>>>(img1, img2, kern, out, inv_n);
}

// Round 4
// 266.168 us; speedup vs baseline: 1.1622x; 1.1622x over previous
//
#include <hip/hip_runtime.h>

#define H 1024
#define W 1024
#define K 11
#define RAD 5
#define ROWS 64              /* output rows per block strip */
#define NIN (ROWS + K - 1)   /* 74 input rows per strip */
#define BW 256               /* columns per block (1 col/thread) */

__global__ void zero_out_kernel(float* out) {
    if (threadIdx.x == 0) out[0] = 0.0f;
}

__device__ __forceinline__ float4 ld4u(const float* p) {
    float4 v;
    __builtin_memcpy(&v, p, sizeof(float4));   // align-4 ok; gfx950 unaligned mode
    return v;
}

__launch_bounds__(256, 4)
__global__ void ssim_kernel(const float* __restrict__ img1,
                            const float* __restrict__ img2,
                            const float* __restrict__ kern,
                            float* __restrict__ out,
                            float inv_n) {
    __shared__ float wsum[4];

    const int tid = threadIdx.x;
    const int col = blockIdx.x * BW + tid;
    const int ry0 = blockIdx.y * ROWS;
    const int b   = blockIdx.z;

    // 1D gaussian = row sums of normalized 2D kernel (exact). Pin to SGPRs.
    float gw[K];
    #pragma unroll
    for (int t = 0; t < K; ++t) {
        float s = 0.0f;
        #pragma unroll
        for (int j = 0; j < K; ++j) s += kern[t * K + j];
        gw[t] = __int_as_float(__builtin_amdgcn_readfirstlane(__float_as_int(s)));
    }

    const float* __restrict__ p1 = img1 + (size_t)b * H * W;
    const float* __restrict__ p2 = img2 + (size_t)b * H * W;
    const bool colfast = (col >= RAD) && (col + 6 < W);   // 12-col window fully in-bounds
    const int rin0 = ry0 - RAD;

    // Ring buffers: 5 planes x 11 rows, statically indexed -> registers.
    float rmx[K], rmy[K], rxx[K], ryy[K], rxy[K];
    float acc = 0.0f;
    const float C1 = 1e-4f;
    const float C2 = 9e-4f;

    for (int base = 0; base < NIN; base += K) {
        #pragma unroll
        for (int p = 0; p < K; ++p) {
            const int i = base + p;
            if (i < NIN) {
                const int r = rin0 + i;
                float x[12], y[12];
                if ((unsigned)r < (unsigned)H) {
                    const float* r1 = p1 + (size_t)r * W;
                    const float* r2 = p2 + (size_t)r * W;
                    if (colfast) {
                        const float* a1 = r1 + (col - RAD);
                        const float* a2 = r2 + (col - RAD);
                        float4 v0 = ld4u(a1);
                        float4 v1 = ld4u(a1 + 4);
                        float4 v2 = ld4u(a1 + 8);
                        float4 u0 = ld4u(a2);
                        float4 u1 = ld4u(a2 + 4);
                        float4 u2 = ld4u(a2 + 8);
                        x[0]=v0.x; x[1]=v0.y; x[2]=v0.z; x[3]=v0.w;
                        x[4]=v1.x; x[5]=v1.y; x[6]=v1.z; x[7]=v1.w;
                        x[8]=v2.x; x[9]=v2.y; x[10]=v2.z; x[11]=v2.w;
                        y[0]=u0.x; y[1]=u0.y; y[2]=u0.z; y[3]=u0.w;
                        y[4]=u1.x; y[5]=u1.y; y[6]=u1.z; y[7]=u1.w;
                        y[8]=u2.x; y[9]=u2.y; y[10]=u2.z; y[11]=u2.w;
                    } else {
                        #pragma unroll
                        for (int m = 0; m < 12; ++m) {
                            const int gc = col - RAD + m;
                            const bool ok = (unsigned)gc < (unsigned)W;
                            x[m] = ok ? r1[gc] : 0.0f;
                            y[m] = ok ? r2[gc] : 0.0f;
                        }
                    }
                } else {
                    #pragma unroll
                    for (int m = 0; m < 12; ++m) { x[m] = 0.0f; y[m] = 0.0f; }
                }

                // Horizontal 11-tap pass -> 5 plane values, store at ring slot p.
                float hmx = 0.f, hmy = 0.f, hxx = 0.f, hyy = 0.f, hxy = 0.f;
                #pragma unroll
                for (int j = 0; j < K; ++j) {
                    const float w  = gw[j];
                    const float xv = x[j];
                    const float yv = y[j];
                    const float wx = w * xv;
                    const float wy = w * yv;
                    hmx += wx;
                    hmy += wy;
                    hxx = fmaf(wx, xv, hxx);
                    hyy = fmaf(wy, yv, hyy);
                    hxy = fmaf(wx, yv, hxy);
                }
                rmx[p] = hmx; rmy[p] = hmy; rxx[p] = hxx; ryy[p] = hyy; rxy[p] = hxy;

                // Vertical 11-tap pass over the ring + SSIM, once primed.
                if (i >= K - 1) {
                    float mx = 0.f, my = 0.f, xx = 0.f, yy = 0.f, xy = 0.f;
                    #pragma unroll
                    for (int j = 0; j < K; ++j) {
                        const int s = (p + 1 + j) % K;   // compile-time after unroll
                        const float w = gw[j];
                        mx = fmaf(w, rmx[s], mx);
                        my = fmaf(w, rmy[s], my);
                        xx = fmaf(w, rxx[s], xx);
                        yy = fmaf(w, ryy[s], yy);
                        xy = fmaf(w, rxy[s], xy);
                    }
                    const float mx2 = mx * mx;
                    const float my2 = my * my;
                    const float mxy = mx * my;
                    const float sx2  = xx - mx2;
                    const float sy2  = yy - my2;
                    const float sxyv = xy - mxy;
                    const float num = (2.0f * mxy + C1) * (2.0f * sxyv + C2);
                    const float den = (mx2 + my2 + C1) * (sx2 + sy2 + C2);
                    acc += num * __builtin_amdgcn_rcpf(den);
                }
            }
        }
    }

    // Wave butterfly reduce -> cross-wave via LDS -> one atomic per block.
    for (int off = 32; off > 0; off >>= 1)
        acc += __shfl_down(acc, off, 64);
    if ((tid & 63) == 0) wsum[tid >> 6] = acc;
    __syncthreads();
    if (tid == 0) {
        const float s = wsum[0] + wsum[1] + wsum[2] + wsum[3];
        atomicAdd(out, s * inv_n);
    }
}

extern "C" void kernel_launch(void* const* d_in, const int* in_sizes, int n_in,
                              void* d_out, int out_size, void* d_ws, size_t ws_size,
                              hipStream_t stream) {
    const float* img1 = (const float*)d_in[0];
    const float* img2 = (const float*)d_in[1];
    const float* kern = (const float*)d_in[2];
    float* out = (float*)d_out;

    const int B = in_sizes[0] / (H * W);
    const float inv_n = 1.0f / ((float)B * (float)H * (float)W);

    zero_out_kernel<<<dim3(1), dim3(64), 0, stream>>>(out);

    dim3 grid(W / BW, H / ROWS, B);
    ssim_kernel<<<grid, dim3(256), 0, stream>>>(img1, img2, kern, out, inv_n);
}

// Round 5
// 257.872 us; speedup vs baseline: 1.1996x; 1.0322x over previous
//
#include <hip/hip_runtime.h>

#define H 1024
#define W 1024
#define K 11
#define RAD 5
#define ROWS 32              /* output rows per block strip */
#define NIN (ROWS + K - 1)   /* 42 input rows per strip */
#define BW 256               /* columns per block (1 col/thread) */

__global__ void zero_out_kernel(float* out) {
    if (threadIdx.x == 0) out[0] = 0.0f;
}

__device__ __forceinline__ float4 ld4u(const float* p) {
    float4 v;
    __builtin_memcpy(&v, p, sizeof(float4));   // 4B-aligned global load
    return v;
}

__launch_bounds__(256, 4)
__global__ void ssim_kernel(const float* __restrict__ img1,
                            const float* __restrict__ img2,
                            const float* __restrict__ kern,
                            float* __restrict__ out,
                            float inv_n) {
    __shared__ float wsum[4];

    const int tid = threadIdx.x;
    const int col = blockIdx.x * BW + tid;
    const int ry0 = blockIdx.y * ROWS;
    const int b   = blockIdx.z;

    // 1D gaussian = row sums of normalized 2D kernel (exact). Pin to SGPRs.
    float gw[K];
    #pragma unroll
    for (int t = 0; t < K; ++t) {
        float s = 0.0f;
        #pragma unroll
        for (int j = 0; j < K; ++j) s += kern[t * K + j];
        gw[t] = __int_as_float(__builtin_amdgcn_readfirstlane(__float_as_int(s)));
    }

    const float* __restrict__ p1 = img1 + (size_t)b * H * W;
    const float* __restrict__ p2 = img2 + (size_t)b * H * W;
    const bool colfast = (col >= RAD) && (col + 6 < W);   // 12-col window in-bounds
    const int rin0 = ry0 - RAD;

    // Ring buffers: 11 rows of H-pass results; float2 packing invites v_pk_fma_f32.
    float2 rmu[K];   // {sum w*x, sum w*y}
    float2 rsq[K];   // {sum w*x*x, sum w*y*y}
    float  rxy[K];   // sum w*x*y
    float acc = 0.0f;
    const float C1 = 1e-4f;
    const float C2 = 9e-4f;

    for (int base = 0; base < NIN; base += K) {
        #pragma unroll
        for (int p = 0; p < K; ++p) {
            const int i = base + p;
            if (i < NIN) {
                const int r = rin0 + i;
                float x[12], y[12];
                if ((unsigned)r < (unsigned)H) {
                    const float* r1 = p1 + (size_t)r * W;
                    const float* r2 = p2 + (size_t)r * W;
                    if (colfast) {
                        const float* a1 = r1 + (col - RAD);
                        const float* a2 = r2 + (col - RAD);
                        float4 v0 = ld4u(a1);
                        float4 v1 = ld4u(a1 + 4);
                        float4 v2 = ld4u(a1 + 8);
                        float4 u0 = ld4u(a2);
                        float4 u1 = ld4u(a2 + 4);
                        float4 u2 = ld4u(a2 + 8);
                        x[0]=v0.x; x[1]=v0.y; x[2]=v0.z; x[3]=v0.w;
                        x[4]=v1.x; x[5]=v1.y; x[6]=v1.z; x[7]=v1.w;
                        x[8]=v2.x; x[9]=v2.y; x[10]=v2.z; x[11]=v2.w;
                        y[0]=u0.x; y[1]=u0.y; y[2]=u0.z; y[3]=u0.w;
                        y[4]=u1.x; y[5]=u1.y; y[6]=u1.z; y[7]=u1.w;
                        y[8]=u2.x; y[9]=u2.y; y[10]=u2.z; y[11]=u2.w;
                    } else {
                        #pragma unroll
                        for (int m = 0; m < 12; ++m) {
                            const int gc = col - RAD + m;
                            const bool ok = (unsigned)gc < (unsigned)W;
                            x[m] = ok ? r1[gc] : 0.0f;
                            y[m] = ok ? r2[gc] : 0.0f;
                        }
                    }
                } else {
                    #pragma unroll
                    for (int m = 0; m < 12; ++m) { x[m] = 0.0f; y[m] = 0.0f; }
                }

                // Horizontal 11-tap pass -> 5 plane values at ring slot p.
                float hmx = 0.f, hmy = 0.f, hxx = 0.f, hyy = 0.f, hxy = 0.f;
                #pragma unroll
                for (int j = 0; j < K; ++j) {
                    const float w  = gw[j];
                    const float xv = x[j];
                    const float yv = y[j];
                    const float wx = w * xv;
                    const float wy = w * yv;
                    hmx += wx;
                    hmy += wy;
                    hxx = fmaf(wx, xv, hxx);
                    hyy = fmaf(wy, yv, hyy);
                    hxy = fmaf(wx, yv, hxy);
                }
                rmu[p] = make_float2(hmx, hmy);
                rsq[p] = make_float2(hxx, hyy);
                rxy[p] = hxy;

                // Vertical 11-tap pass over the ring + SSIM, once primed.
                if (i >= K - 1) {
                    float2 mu = make_float2(0.f, 0.f);
                    float2 sq = make_float2(0.f, 0.f);
                    float  xy = 0.f;
                    #pragma unroll
                    for (int j = 0; j < K; ++j) {
                        const int s = (p + 1 + j) % K;   // compile-time after unroll
                        const float w = gw[j];
                        mu.x = fmaf(w, rmu[s].x, mu.x);
                        mu.y = fmaf(w, rmu[s].y, mu.y);
                        sq.x = fmaf(w, rsq[s].x, sq.x);
                        sq.y = fmaf(w, rsq[s].y, sq.y);
                        xy   = fmaf(w, rxy[s],   xy);
                    }
                    const float mx2 = mu.x * mu.x;
                    const float my2 = mu.y * mu.y;
                    const float mxy = mu.x * mu.y;
                    const float sx2  = sq.x - mx2;
                    const float sy2  = sq.y - my2;
                    const float sxyv = xy - mxy;
                    const float num = (2.0f * mxy + C1) * (2.0f * sxyv + C2);
                    const float den = (mx2 + my2 + C1) * (sx2 + sy2 + C2);
                    acc += num * __builtin_amdgcn_rcpf(den);
                }
            }
        }
    }

    // Wave butterfly reduce -> cross-wave via LDS -> one atomic per block.
    for (int off = 32; off > 0; off >>= 1)
        acc += __shfl_down(acc, off, 64);
    if ((tid & 63) == 0) wsum[tid >> 6] = acc;
    __syncthreads();
    if (tid == 0) {
        const float s = wsum[0] + wsum[1] + wsum[2] + wsum[3];
        atomicAdd(out, s * inv_n);
    }
}

extern "C" void kernel_launch(void* const* d_in, const int* in_sizes, int n_in,
                              void* d_out, int out_size, void* d_ws, size_t ws_size,
                              hipStream_t stream) {
    const float* img1 = (const float*)d_in[0];
    const float* img2 = (const float*)d_in[1];
    const float* kern = (const float*)d_in[2];
    float* out = (float*)d_out;

    const int B = in_sizes[0] / (H * W);
    const float inv_n = 1.0f / ((float)B * (float)H * (float)W);

    zero_out_kernel<<<dim3(1), dim3(64), 0, stream>>>(out);

    dim3 grid(W / BW, H / ROWS, B);
    ssim_kernel<<<grid, dim3(256), 0, stream>>>(img1, img2, kern, out, inv_n);
}

// Round 6
// 232.974 us; speedup vs baseline: 1.3278x; 1.1069x over previous
//
#include <hip/hip_runtime.h>

#define H 1024
#define W 1024
#define K 11
#define RAD 5
#define ROWS 64              /* output rows per block strip */
#define NIN (ROWS + K - 1)   /* 74 input rows per strip */
#define BW 256               /* columns per block (1 col/thread) */

typedef float v2f __attribute__((ext_vector_type(2)));

__global__ void zero_out_kernel(float* out) {
    if (threadIdx.x == 0) out[0] = 0.0f;
}

__device__ __forceinline__ float4 ld4u(const float* p) {
    float4 v;
    __builtin_memcpy(&v, p, sizeof(float4));
    return v;
}

__device__ __forceinline__ v2f pkfma(v2f a, v2f b, v2f c) {
    return __builtin_elementwise_fma(a, b, c);
}

template<bool FAST>
__device__ __forceinline__ void load_row(const float* __restrict__ r1,
                                         const float* __restrict__ r2,
                                         int col, float* x, float* y) {
    if (FAST) {
        const float* a1 = r1 + (col - RAD);
        const float* a2 = r2 + (col - RAD);
        float4 v0 = ld4u(a1), v1 = ld4u(a1 + 4), v2 = ld4u(a1 + 8);
        float4 u0 = ld4u(a2), u1 = ld4u(a2 + 4), u2 = ld4u(a2 + 8);
        x[0]=v0.x; x[1]=v0.y; x[2]=v0.z; x[3]=v0.w;
        x[4]=v1.x; x[5]=v1.y; x[6]=v1.z; x[7]=v1.w;
        x[8]=v2.x; x[9]=v2.y; x[10]=v2.z; x[11]=v2.w;
        y[0]=u0.x; y[1]=u0.y; y[2]=u0.z; y[3]=u0.w;
        y[4]=u1.x; y[5]=u1.y; y[6]=u1.z; y[7]=u1.w;
        y[8]=u2.x; y[9]=u2.y; y[10]=u2.z; y[11]=u2.w;
    } else {
        #pragma unroll
        for (int m = 0; m < 12; ++m) {
            const int gc = col - RAD + m;
            const bool ok = (unsigned)gc < (unsigned)W;
            x[m] = ok ? r1[gc] : 0.0f;
            y[m] = ok ? r2[gc] : 0.0f;
        }
    }
}

template<bool FAST>
__device__ __forceinline__ float run_strip(const float* __restrict__ p1,
                                           const float* __restrict__ p2,
                                           int col, int rin0, const float* gw) {
    // Packed rings: {mu_x,mu_y}, {xx,yy} pairs + scalar xy. 55 floats, static idx.
    v2f  rmu[K], rsq[K];
    float rxy[K];
    float acc = 0.0f;
    const float C1 = 1e-4f;
    const float C2 = 9e-4f;

    for (int base = 0; base < NIN; base += K) {
        #pragma unroll
        for (int p = 0; p < K; ++p) {
            const int i = base + p;
            if (i < NIN) {
                const int r  = rin0 + i;                       // block-uniform
                const int rr = min(max(r, 0), H - 1);          // clamped (valid addr)
                const float s = ((unsigned)r < (unsigned)H) ? 1.0f : 0.0f;

                float x[12], y[12];
                load_row<FAST>(p1 + (size_t)rr * W, p2 + (size_t)rr * W, col, x, y);

                // ---- Horizontal 11-tap, tap-paired packed fp32 ----
                v2f amx = {0.f,0.f}, amy = {0.f,0.f};
                v2f axx = {0.f,0.f}, ayy = {0.f,0.f}, axy = {0.f,0.f};
                #pragma unroll
                for (int e = 0; e < 5; ++e) {
                    v2f w2 = { gw[2*e], gw[2*e+1] };
                    v2f xp = { x[2*e], x[2*e+1] };
                    v2f yp = { y[2*e], y[2*e+1] };
                    v2f wxp = w2 * xp;
                    v2f wyp = w2 * yp;
                    amx += wxp;
                    amy += wyp;
                    axx = pkfma(wxp, xp, axx);
                    ayy = pkfma(wyp, yp, ayy);
                    axy = pkfma(wxp, yp, axy);
                }
                const float twx = gw[10] * x[10];
                const float twy = gw[10] * y[10];
                const float hmx = (amx.x + amx.y) + twx;
                const float hmy = (amy.x + amy.y) + twy;
                const float hxx = fmaf(twx, x[10], axx.x + axx.y);
                const float hyy = fmaf(twy, y[10], ayy.x + ayy.y);
                const float hxy = fmaf(twx, y[10], axy.x + axy.y);

                v2f s2 = { s, s };
                rmu[p] = s2 * (v2f){ hmx, hmy };
                rsq[p] = s2 * (v2f){ hxx, hyy };
                rxy[p] = s * hxy;

                // ---- Vertical 11-tap, plane-paired packed + SSIM ----
                if (i >= K - 1) {
                    v2f mu = {0.f,0.f}, sq = {0.f,0.f};
                    float xy = 0.f;
                    #pragma unroll
                    for (int j = 0; j < K; ++j) {
                        const int sl = (p + 1 + j) % K;        // static after unroll
                        const float w = gw[j];
                        v2f w2 = { w, w };
                        mu = pkfma(w2, rmu[sl], mu);
                        sq = pkfma(w2, rsq[sl], sq);
                        xy = fmaf(w, rxy[sl], xy);
                    }
                    v2f m2 = mu * mu;                          // {mx2, my2}
                    const float mxy  = mu.x * mu.y;
                    v2f sg = sq - m2;                          // {sx2, sy2}
                    const float sxyv = xy - mxy;
                    const float num = fmaf(2.0f, mxy,  C1) * fmaf(2.0f, sxyv, C2);
                    const float den = (m2.x + m2.y + C1) * (sg.x + sg.y + C2);
                    acc += num * __builtin_amdgcn_rcpf(den);
                }
            }
        }
    }
    return acc;
}

__launch_bounds__(256, 2)
__global__ void ssim_kernel(const float* __restrict__ img1,
                            const float* __restrict__ img2,
                            const float* __restrict__ kern,
                            float* __restrict__ out,
                            float inv_n) {
    __shared__ float wsum[4];

    const int tid = threadIdx.x;
    const int col = blockIdx.x * BW + tid;
    const int ry0 = blockIdx.y * ROWS;
    const int b   = blockIdx.z;

    // 1D gaussian = row sums of normalized 2D kernel (exact). Pin to SGPRs.
    float gw[K];
    #pragma unroll
    for (int t = 0; t < K; ++t) {
        float s = 0.0f;
        #pragma unroll
        for (int j = 0; j < K; ++j) s += kern[t * K + j];
        gw[t] = __int_as_float(__builtin_amdgcn_readfirstlane(__float_as_int(s)));
    }

    const float* __restrict__ p1 = img1 + (size_t)b * H * W;
    const float* __restrict__ p2 = img2 + (size_t)b * H * W;
    const int rin0 = ry0 - RAD;

    // Wave-uniform fast/slow split: fast iff ALL lanes' 12-col windows in-bounds.
    const bool colfast = (col >= RAD) && (col + RAD + 1 < W);
    const unsigned long long bal = __ballot(colfast);
    float acc;
    if (bal == ~0ULL) {
        acc = run_strip<true>(p1, p2, col, rin0, gw);
    } else {
        acc = run_strip<false>(p1, p2, col, rin0, gw);
    }

    // Wave butterfly reduce -> cross-wave via LDS -> one atomic per block.
    for (int off = 32; off > 0; off >>= 1)
        acc += __shfl_down(acc, off, 64);
    if ((tid & 63) == 0) wsum[tid >> 6] = acc;
    __syncthreads();
    if (tid == 0) {
        const float s = wsum[0] + wsum[1] + wsum[2] + wsum[3];
        atomicAdd(out, s * inv_n);
    }
}

extern "C" void kernel_launch(void* const* d_in, const int* in_sizes, int n_in,
                              void* d_out, int out_size, void* d_ws, size_t ws_size,
                              hipStream_t stream) {
    const float* img1 = (const float*)d_in[0];
    const float* img2 = (const float*)d_in[1];
    const float* kern = (const float*)d_in[2];
    float* out = (float*)d_out;

    const int B = in_sizes[0] / (H * W);
    const float inv_n = 1.0f / ((float)B * (float)H * (float)W);

    zero_out_kernel<<<dim3(1), dim3(64), 0, stream>>>(out);

    dim3 grid(W / BW, H / ROWS, B);
    ssim_kernel<<<grid, dim3(256), 0, stream>>>(img1, img2, kern, out, inv_n);
}